// Round 11
// baseline (447.606 us; speedup 1.0000x reference)
//
#include <hip/hip_runtime.h>
#include <hip/hip_bf16.h>

#define T_LEN 96
#define C_CH  66
#define FIN   7128   // 9*66*12
#define KPAD  7168   // 224*32
#define NFC1  1936
#define NPAD  2048
#define NCLS  14

typedef __bf16 bf16x8 __attribute__((ext_vector_type(8)));
typedef float  f32x4  __attribute__((ext_vector_type(4)));

#define GLD_LDS(gp, lp) __builtin_amdgcn_global_load_lds(                     \
    (__attribute__((address_space(1))) void*)(gp),                            \
    (__attribute__((address_space(3))) void*)(lp), 16, 0, 0)

// ---------------------------------------------------------------------------
// Kernel 0: transpose x (B, T*C) -> xT (T*C, B) so conv lanes (lane=b) read
// coalesced. 64x64 LDS tile, +1 pad.
__global__ __launch_bounds__(256) void transpose_kernel(
    const float* __restrict__ x, float* __restrict__ xT, int B)
{
    __shared__ float tile[64][65];
    const int t = threadIdx.x & 63;
    const int w = threadIdx.x >> 6;
    const int tc0 = blockIdx.x * 64;     // 6336 / 64 = 99
    const int b0  = blockIdx.y * 64;     // B / 64
    #pragma unroll
    for (int j = 0; j < 16; j++) {
        const int r = w * 16 + j;
        tile[r][t] = x[(size_t)(b0 + r) * (T_LEN * C_CH) + tc0 + t];
    }
    __syncthreads();
    #pragma unroll
    for (int j = 0; j < 16; j++) {
        const int r = w * 16 + j;
        xT[(size_t)(tc0 + r) * B + b0 + t] = tile[t][r];
    }
}

// ---------------------------------------------------------------------------
// Kernel 1: w_fc1 (1936 x 7128 fp32) -> bf16 (2048 x 7168), zero padded.
__global__ __launch_bounds__(256) void pad_w_kernel(
    const float* __restrict__ w, __hip_bfloat16* __restrict__ wb)
{
    int idx = blockIdx.x * 256 + threadIdx.x;     // chunk id, total 2048*896
    int row = idx / 896;
    int cc  = idx - row * 896;                    // 896 chunks of 8 per row
    float4 a = {0.f, 0.f, 0.f, 0.f}, b = {0.f, 0.f, 0.f, 0.f};
    if (row < NFC1 && cc < 891) {                 // 891*8 = 7128
        const float4* src = (const float4*)(w + (size_t)row * FIN + cc * 8);
        a = src[0];
        b = src[1];
    }
    __align__(16) __hip_bfloat16 v[8];
    v[0] = __float2bfloat16(a.x); v[1] = __float2bfloat16(a.y);
    v[2] = __float2bfloat16(a.z); v[3] = __float2bfloat16(a.w);
    v[4] = __float2bfloat16(b.x); v[5] = __float2bfloat16(b.y);
    v[6] = __float2bfloat16(b.z); v[7] = __float2bfloat16(b.w);
    *(int4*)(wb + (size_t)row * KPAD + cc * 8) = *(const int4*)v;
}

// ---------------------------------------------------------------------------
// Kernel 2: conv branches — inner conv_branch EXACT round-0 version (VGPR=
// 128, known good; DO NOT TOUCH — 5 codegen interventions all lost).
// ROUND-11: SPLIT INTO TWO KERNELS (K=7-only, K=3-only). Theory: per-wave
// issue is pinned at ~36% regardless of residency (r0/r7/r8) — not BW, not
// chains, not LDS. Remaining candidate: I-cache. Combined kernel = both
// fully-unrolled branch bodies (~25-50KB) resident per CU (mixed blockIdx.z)
// vs 32KB L1I -> steady-state fetch misses. Splitting gives each launch a
// single-branch working set (~15-25KB, fits). conv_branch codegen unchanged.
template <int K, bool DO_EXTRA>
__device__ __forceinline__ void conv_branch(
    const float* __restrict__ xb, int ts,
    const float* __restrict__ wS, const float* __restrict__ bS,
    const float* __restrict__ wi1, const float* __restrict__ bi1,
    const float* __restrict__ wi2, const float* __restrict__ bi2,
    __hip_bfloat16* __restrict__ frow, int out_off)
{
    constexpr int PAD = K / 2;
    constexpr int XW  = 24 + 6 * PAD;   // x window per tile
    constexpr int THW = 12 + 2 * PAD;   // stage-1 pooled window per tile

    float s2phR[4][24];                 // stage-2 pooled (static indices)

    #pragma unroll
    for (int tt = 0; tt < 4; tt++) {    // fully unrolled: all indices const
        // x window: global t = 24*tt - 3*PAD + i (zero outside [0,96))
        float xw[XW];
        #pragma unroll
        for (int i = 0; i < XW; i++) {
            const int t = 24 * tt - 3 * PAD + i;     // compile-time
            xw[i] = (t >= 0 && t < T_LEN) ? xb[(size_t)t * ts] : 0.f;
        }

        if (DO_EXTRA) {                 // orig = pool2^3: 3 outputs per tile
            #pragma unroll
            for (int r = 0; r < 3; r++) {
                float s = 0.f;
                #pragma unroll
                for (int k = 0; k < 8; k++) s += xw[3 * PAD + 8 * r + k];
                frow[3 * tt + r] = __float2bfloat16(s * 0.125f);
            }
        }

        float s2a[4][12];
        #pragma unroll
        for (int oc = 0; oc < 4; oc++) {
            const float bv = bi1[oc];
            #pragma unroll
            for (int q = 0; q < 12; q++) s2a[oc][q] = bv;
        }

        #pragma unroll 1
        for (int ic = 0; ic < 8; ic++) {
            const float bs1 = bS[ic];
            float thw[THW];             // stage-1 pooled window (this ic)
            #pragma unroll
            for (int j = 0; j < THW; j++) {
                const int jg = 12 * tt - PAD + j;    // compile-time
                if (jg < 0 || jg >= 48) { thw[j] = 0.f; continue; }
                float y0 = bs1, y1 = bs1;
                #pragma unroll
                for (int k = 0; k < K; k++) {
                    const float w = wS[ic * K + k];
                    y0 = fmaf(w, xw[2 * j + k], y0);
                    y1 = fmaf(w, xw[2 * j + 1 + k], y1);
                }
                thw[j] = 0.5f * (fmaxf(y0, 0.f) + fmaxf(y1, 0.f));
            }
            #pragma unroll
            for (int q = 0; q < 12; q++) {
                #pragma unroll
                for (int oc = 0; oc < 4; oc++) {
                    float a = s2a[oc][q];
                    #pragma unroll
                    for (int k = 0; k < K; k++)
                        a = fmaf(wi1[(oc * 8 + ic) * K + k], thw[q + k], a);
                    s2a[oc][q] = a;
                }
            }
        }

        // pool stage 2 -> s2phR[oc][6*tt + r]
        #pragma unroll
        for (int oc = 0; oc < 4; oc++)
            #pragma unroll
            for (int r = 0; r < 6; r++)
                s2phR[oc][6 * tt + r] =
                    0.5f * (fmaxf(s2a[oc][2 * r], 0.f) +
                            fmaxf(s2a[oc][2 * r + 1], 0.f));
    }

    // stage 3 (grouped 4->4) + relu + pool2; OOB taps statically dropped
    #pragma unroll 1
    for (int oc = 0; oc < 4; oc++) {
        const float bv = bi2[oc];
        #pragma unroll
        for (int q = 0; q < 12; q++) {
            float y0 = bv, y1 = bv;
            #pragma unroll
            for (int ic = 0; ic < 4; ic++) {
                #pragma unroll
                for (int k = 0; k < K; k++) {
                    const float w = wi2[(oc * 4 + ic) * K + k];
                    const int i0 = 2 * q + k - PAD;       // compile-time
                    const int i1 = 2 * q + 1 + k - PAD;
                    if (i0 >= 0 && i0 < 24) y0 = fmaf(w, s2phR[ic][i0], y0);
                    if (i1 >= 0 && i1 < 24) y1 = fmaf(w, s2phR[ic][i1], y1);
                }
            }
            frow[out_off + oc * 12 + q] =
                __float2bfloat16(0.5f * (fmaxf(y0, 0.f) + fmaxf(y1, 0.f)));
        }
    }
}

__global__ __launch_bounds__(64, 2) void conv_high_kernel(
    const float* __restrict__ x, int ts, int bs, int cs,
    const float* __restrict__ w_hs, const float* __restrict__ b_hs,
    const float* __restrict__ w_hi1, const float* __restrict__ b_hi1,
    const float* __restrict__ w_hi2, const float* __restrict__ b_hi2,
    __hip_bfloat16* __restrict__ feat)
{
    const int lane = threadIdx.x;
    const int b = blockIdx.x * 64 + lane;
    const int c = blockIdx.y;
    const float* xb = x + (size_t)b * bs + (size_t)c * cs;
    __hip_bfloat16* frow = feat + (size_t)b * KPAD + c * 108;
    conv_branch<7, false>(xb, ts, w_hs, b_hs,
                          w_hi1 + c * 224, b_hi1 + c * 4,
                          w_hi2 + c * 112, b_hi2 + c * 4, frow, 60);
}

__global__ __launch_bounds__(64, 2) void conv_low_kernel(
    const float* __restrict__ x, int ts, int bs, int cs,
    const float* __restrict__ w_ls, const float* __restrict__ b_ls,
    const float* __restrict__ w_li1, const float* __restrict__ b_li1,
    const float* __restrict__ w_li2, const float* __restrict__ b_li2,
    __hip_bfloat16* __restrict__ feat)
{
    const int lane = threadIdx.x;
    const int b = blockIdx.x * 64 + lane;
    const int c = blockIdx.y;
    const float* xb = x + (size_t)b * bs + (size_t)c * cs;
    __hip_bfloat16* frow = feat + (size_t)b * KPAD + c * 108;
    if (c == 0) {                       // zero K-pad tail once per row
        int4* tail = (int4*)(feat + (size_t)b * KPAD + FIN);
        const int4 z = {0, 0, 0, 0};
        #pragma unroll
        for (int i = 0; i < 5; i++) tail[i] = z;
    }
    conv_branch<3, true>(xb, ts, w_ls, b_ls,
                         w_li1 + c * 96, b_li1 + c * 4,
                         w_li2 + c * 48, b_li2 + c * 4, frow, 12);
}

// ---------------------------------------------------------------------------
// Kernel 3: FC1 GEMM. 8-phase-style interleave (T3+T4+T5), verified r10
// (total -17us vs 2-phase). 256x256, BK=64, 4 subphases/K-tile, half-tiles
// staged along K ([dbuf][op][kh][256*32] contiguous -> GLD_LDS legal),
// vmcnt(4) at barriers keeps 2 half-tiles in flight, setprio around MFMA.
__global__ __launch_bounds__(512, 2) void gemm_kernel(
    const __hip_bfloat16* __restrict__ A,
    const __hip_bfloat16* __restrict__ Bw,
    float* __restrict__ Cm, int kchunk)
{
    __shared__ __align__(16) __hip_bfloat16 lds[2][2][2][8192];  // 128 KiB

    const int tid  = threadIdx.x;
    const int lane = tid & 63;
    const int wid  = tid >> 6;          // 0..7
    const int m0 = blockIdx.y * 256;
    const int n0 = blockIdx.x * 256;
    const int wm = (wid >> 2) * 128;    // 2 wave-rows (128 each)
    const int wn = (wid & 3) * 64;      // 4 wave-cols (64 each)
    const int lr = lane & 15;
    const int quad = lane >> 4;

    const int srow = tid >> 2, scol = (tid & 3) * 8;
    const __hip_bfloat16* gA = A  + (size_t)(m0 + srow) * KPAD + scol;
    const __hip_bfloat16* gB = Bw + (size_t)(n0 + srow) * KPAD + scol;

    f32x4 acc[8][4] = {};

    const int kBeg = blockIdx.z * kchunk;
    const int numt = kchunk >> 6;       // K-steps of 64 (28 for sk=4)

#define STAGE_H(opidx, gptr, kh, kt)                                          \
    do {                                                                      \
        const size_t co = (size_t)(kBeg + (kt) * 64 + (kh) * 32);             \
        GLD_LDS((gptr) + co, &lds[(kt) & 1][opidx][kh][wid * 512]);           \
        GLD_LDS((gptr) + co + (size_t)128 * KPAD,                             \
                &lds[(kt) & 1][opidx][kh][4096 + wid * 512]);                 \
    } while (0)

    // prologue: stage tile 0's 4 half-tiles in H-stream order
    STAGE_H(0, gA, 0, 0);
    STAGE_H(1, gB, 0, 0);
    STAGE_H(0, gA, 1, 0);
    STAGE_H(1, gB, 1, 0);

    for (int t = 0; t < numt; ++t) {
        const int p = t & 1;
        const bool pf = (t + 1 < numt);

        // ===== entry 0: guards ks=0 data (A-kh0, B-kh0 of tile t) =====
        if (pf) asm volatile("s_waitcnt vmcnt(4)" ::: "memory");
        else    asm volatile("s_waitcnt vmcnt(0)" ::: "memory");
        __builtin_amdgcn_sched_barrier(0);
        __builtin_amdgcn_s_barrier();
        __builtin_amdgcn_sched_barrier(0);
        {
            bf16x8 bfr[4], af[4];
            #pragma unroll
            for (int nn = 0; nn < 4; nn++)
                bfr[nn] = *(const bf16x8*)&lds[p][1][0][
                    (wn + nn * 16 + lr) * 32 + quad * 8];
            #pragma unroll
            for (int i = 0; i < 4; i++)
                af[i] = *(const bf16x8*)&lds[p][0][0][
                    (wm + i * 16 + lr) * 32 + quad * 8];
            if (pf) STAGE_H(0, gA, 0, t + 1);      // H[4(t+1)+0]
            __builtin_amdgcn_s_setprio(1);
            #pragma unroll
            for (int i = 0; i < 4; i++)
                #pragma unroll
                for (int nn = 0; nn < 4; nn++)
                    acc[i][nn] = __builtin_amdgcn_mfma_f32_16x16x32_bf16(
                        af[i], bfr[nn], acc[i][nn], 0, 0, 0);
            __builtin_amdgcn_s_setprio(0);

            // subphase q1: ks0, mt 4-7 (reuse bfr)
            #pragma unroll
            for (int i = 0; i < 4; i++)
                af[i] = *(const bf16x8*)&lds[p][0][0][
                    (wm + 64 + i * 16 + lr) * 32 + quad * 8];
            if (pf) STAGE_H(1, gB, 0, t + 1);      // H[4(t+1)+1]
            __builtin_amdgcn_s_setprio(1);
            #pragma unroll
            for (int i = 0; i < 4; i++)
                #pragma unroll
                for (int nn = 0; nn < 4; nn++)
                    acc[4 + i][nn] = __builtin_amdgcn_mfma_f32_16x16x32_bf16(
                        af[i], bfr[nn], acc[4 + i][nn], 0, 0, 0);
            __builtin_amdgcn_s_setprio(0);
        }

        // ===== entry 1: guards ks=1 data (A-kh1, B-kh1 of tile t) =====
        if (pf) asm volatile("s_waitcnt vmcnt(4)" ::: "memory");
        else    asm volatile("s_waitcnt vmcnt(0)" ::: "memory");
        __builtin_amdgcn_sched_barrier(0);
        __builtin_amdgcn_s_barrier();
        __builtin_amdgcn_sched_barrier(0);
        {
            bf16x8 bfr[4], af[4];
            #pragma unroll
            for (int nn = 0; nn < 4; nn++)
                bfr[nn] = *(const bf16x8*)&lds[p][1][1][
                    (wn + nn * 16 + lr) * 32 + quad * 8];
            #pragma unroll
            for (int i = 0; i < 4; i++)
                af[i] = *(const bf16x8*)&lds[p][0][1][
                    (wm + i * 16 + lr) * 32 + quad * 8];
            if (pf) STAGE_H(0, gA, 1, t + 1);      // H[4(t+1)+2]
            __builtin_amdgcn_s_setprio(1);
            #pragma unroll
            for (int i = 0; i < 4; i++)
                #pragma unroll
                for (int nn = 0; nn < 4; nn++)
                    acc[i][nn] = __builtin_amdgcn_mfma_f32_16x16x32_bf16(
                        af[i], bfr[nn], acc[i][nn], 0, 0, 0);
            __builtin_amdgcn_s_setprio(0);

            // subphase q3: ks1, mt 4-7 (reuse bfr)
            #pragma unroll
            for (int i = 0; i < 4; i++)
                af[i] = *(const bf16x8*)&lds[p][0][1][
                    (wm + 64 + i * 16 + lr) * 32 + quad * 8];
            if (pf) STAGE_H(1, gB, 1, t + 1);      // H[4(t+1)+3]
            __builtin_amdgcn_s_setprio(1);
            #pragma unroll
            for (int i = 0; i < 4; i++)
                #pragma unroll
                for (int nn = 0; nn < 4; nn++)
                    acc[4 + i][nn] = __builtin_amdgcn_mfma_f32_16x16x32_bf16(
                        af[i], bfr[nn], acc[4 + i][nn], 0, 0, 0);
            __builtin_amdgcn_s_setprio(0);
        }
    }
#undef STAGE_H

    // epilogue: C/D layout col = lane&15, row = quad*4 + reg
    float* Cs = Cm + (size_t)blockIdx.z * NPAD * NPAD;
    #pragma unroll
    for (int mt = 0; mt < 8; mt++) {
        #pragma unroll
        for (int nn = 0; nn < 4; nn++) {
            const int col = n0 + wn + nn * 16 + lr;
            const int rb  = m0 + wm + mt * 16 + quad * 4;
            #pragma unroll
            for (int r = 0; r < 4; r++)
                Cs[(size_t)(rb + r) * NPAD + col] = acc[mt][nn][r];
        }
    }
}

// ---------------------------------------------------------------------------
// Kernel 4: reduce split-K slabs + bias + relu, then FC2. One block per row.
__global__ __launch_bounds__(256) void fc2_kernel(
    const float* __restrict__ h1, const float* __restrict__ b1,
    const float* __restrict__ w2, const float* __restrict__ b2,
    float* __restrict__ out, int nslab)
{
    const int b = blockIdx.x;
    const int tid = threadIdx.x;
    float acc[NCLS];
    #pragma unroll
    for (int o = 0; o < NCLS; o++) acc[o] = 0.f;
    for (int n = tid; n < NFC1; n += 256) {
        float hv = b1[n];
        for (int s = 0; s < nslab; s++)
            hv += h1[(size_t)s * NPAD * NPAD + (size_t)b * NPAD + n];
        float h = fmaxf(hv, 0.f);
        #pragma unroll
        for (int o = 0; o < NCLS; o++)
            acc[o] = fmaf(h, w2[o * NFC1 + n], acc[o]);
    }
    __shared__ float red[4][NCLS];
    #pragma unroll
    for (int o = 0; o < NCLS; o++) {
        float v = acc[o];
        #pragma unroll
        for (int s = 32; s > 0; s >>= 1) v += __shfl_down(v, s);
        if ((tid & 63) == 0) red[tid >> 6][o] = v;
    }
    __syncthreads();
    if (tid < NCLS)
        out[b * NCLS + tid] = red[0][tid] + red[1][tid] + red[2][tid] +
                              red[3][tid] + b2[tid];
}

// ---------------------------------------------------------------------------
extern "C" void kernel_launch(void* const* d_in, const int* in_sizes, int n_in,
                              void* d_out, int out_size, void* d_ws, size_t ws_size,
                              hipStream_t stream)
{
    (void)n_in; (void)out_size;
    const float* x     = (const float*)d_in[0];
    const float* w_hs  = (const float*)d_in[1];
    const float* b_hs  = (const float*)d_in[2];
    const float* w_ls  = (const float*)d_in[3];
    const float* b_ls  = (const float*)d_in[4];
    const float* w_hi1 = (const float*)d_in[5];
    const float* b_hi1 = (const float*)d_in[6];
    const float* w_hi2 = (const float*)d_in[7];
    const float* b_hi2 = (const float*)d_in[8];
    const float* w_li1 = (const float*)d_in[9];
    const float* b_li1 = (const float*)d_in[10];
    const float* w_li2 = (const float*)d_in[11];
    const float* b_li2 = (const float*)d_in[12];
    const float* w_fc1 = (const float*)d_in[13];
    const float* b_fc1 = (const float*)d_in[14];
    const float* w_fc2 = (const float*)d_in[15];
    const float* b_fc2 = (const float*)d_in[16];
    float* out = (float*)d_out;

    const int B = in_sizes[0] / (T_LEN * C_CH);    // 2048

    char* ws = (char*)d_ws;
    const size_t featB = (size_t)B * KPAD * 2;         // 29.4 MB
    const size_t wbB   = (size_t)NPAD * KPAD * 2;      // 29.4 MB
    const size_t slabB = (size_t)NPAD * NPAD * 4;      // 16.8 MB
    const size_t xtB   = (size_t)T_LEN * C_CH * B * 4; // 51.9 MB
    const size_t base2 = featB + wbB;

    __hip_bfloat16* feat = (__hip_bfloat16*)ws;
    __hip_bfloat16* wb   = (__hip_bfloat16*)(ws + featB);
    float* h1            = (float*)(ws + base2);

    const int sk = (ws_size >= base2 + 4 * slabB) ? 4 : 2;
    const bool use_xt = (ws_size >= base2 + sk * slabB + xtB);
    float* xT = (float*)(ws + base2 + sk * slabB);

    pad_w_kernel<<<dim3((NPAD * 896) / 256), 256, 0, stream>>>(w_fc1, wb);

    const float* cx = x;
    int ts = C_CH, bsi = T_LEN * C_CH, cs = 1;
    if (use_xt) {
        transpose_kernel<<<dim3(99, B / 64), 256, 0, stream>>>(x, xT, B);
        cx = xT; ts = C_CH * B; bsi = 1; cs = B;
    }
    conv_high_kernel<<<dim3(B / 64, C_CH), 64, 0, stream>>>(
        cx, ts, bsi, cs, w_hs, b_hs, w_hi1, b_hi1, w_hi2, b_hi2, feat);
    conv_low_kernel<<<dim3(B / 64, C_CH), 64, 0, stream>>>(
        cx, ts, bsi, cs, w_ls, b_ls, w_li1, b_li1, w_li2, b_li2, feat);
    gemm_kernel<<<dim3(NPAD / 256, B / 256, sk), 512, 0, stream>>>(
        feat, wb, h1, KPAD / sk);
    fc2_kernel<<<dim3(B), 256, 0, stream>>>(h1, b_fc1, w_fc2, b_fc2, out, sk);
}

// Round 12
// 404.218 us; speedup vs baseline: 1.1073x; 1.1073x over previous
//
#include <hip/hip_runtime.h>
#include <hip/hip_bf16.h>

#define T_LEN 96
#define C_CH  66
#define FIN   7128   // 9*66*12
#define KPAD  7168   // 224*32
#define NFC1  1936
#define NPAD  2048
#define NCLS  14

typedef __bf16 bf16x8 __attribute__((ext_vector_type(8)));
typedef float  f32x4  __attribute__((ext_vector_type(4)));

#define GLD_LDS(gp, lp) __builtin_amdgcn_global_load_lds(                     \
    (__attribute__((address_space(1))) void*)(gp),                            \
    (__attribute__((address_space(3))) void*)(lp), 16, 0, 0)

// ---------------------------------------------------------------------------
// Kernel 0: transpose x (B, T*C) -> xT (T*C, B) so conv lanes (lane=b) read
// coalesced. 64x64 LDS tile, +1 pad.
__global__ __launch_bounds__(256) void transpose_kernel(
    const float* __restrict__ x, float* __restrict__ xT, int B)
{
    __shared__ float tile[64][65];
    const int t = threadIdx.x & 63;
    const int w = threadIdx.x >> 6;
    const int tc0 = blockIdx.x * 64;     // 6336 / 64 = 99
    const int b0  = blockIdx.y * 64;     // B / 64
    #pragma unroll
    for (int j = 0; j < 16; j++) {
        const int r = w * 16 + j;
        tile[r][t] = x[(size_t)(b0 + r) * (T_LEN * C_CH) + tc0 + t];
    }
    __syncthreads();
    #pragma unroll
    for (int j = 0; j < 16; j++) {
        const int r = w * 16 + j;
        xT[(size_t)(tc0 + r) * B + b0 + t] = tile[t][r];
    }
}

// ---------------------------------------------------------------------------
// Kernel 1: w_fc1 (1936 x 7128 fp32) -> bf16 (2048 x 7168), zero padded.
__global__ __launch_bounds__(256) void pad_w_kernel(
    const float* __restrict__ w, __hip_bfloat16* __restrict__ wb)
{
    int idx = blockIdx.x * 256 + threadIdx.x;     // chunk id, total 2048*896
    int row = idx / 896;
    int cc  = idx - row * 896;                    // 896 chunks of 8 per row
    float4 a = {0.f, 0.f, 0.f, 0.f}, b = {0.f, 0.f, 0.f, 0.f};
    if (row < NFC1 && cc < 891) {                 // 891*8 = 7128
        const float4* src = (const float4*)(w + (size_t)row * FIN + cc * 8);
        a = src[0];
        b = src[1];
    }
    __align__(16) __hip_bfloat16 v[8];
    v[0] = __float2bfloat16(a.x); v[1] = __float2bfloat16(a.y);
    v[2] = __float2bfloat16(a.z); v[3] = __float2bfloat16(a.w);
    v[4] = __float2bfloat16(b.x); v[5] = __float2bfloat16(b.y);
    v[6] = __float2bfloat16(b.z); v[7] = __float2bfloat16(b.w);
    *(int4*)(wb + (size_t)row * KPAD + cc * 8) = *(const int4*)v;
}

// ---------------------------------------------------------------------------
// Kernel 2: conv branches — EXACT round-0 version (174us, VGPR=128), both
// branches in ONE launch (blockIdx.z) so they run CONCURRENTLY. DO NOT
// TOUCH: 6 interventions tried; r11's split proved I-cache costs ~16% of
// per-wave issue but serialization of the two branches costs more.
// One lane = one (b, c); grid (B/64, C, 2): z=0 K=7, z=1 K=3.
template <int K, bool DO_EXTRA>
__device__ __forceinline__ void conv_branch(
    const float* __restrict__ xb, int ts,
    const float* __restrict__ wS, const float* __restrict__ bS,
    const float* __restrict__ wi1, const float* __restrict__ bi1,
    const float* __restrict__ wi2, const float* __restrict__ bi2,
    __hip_bfloat16* __restrict__ frow, int out_off)
{
    constexpr int PAD = K / 2;
    constexpr int XW  = 24 + 6 * PAD;   // x window per tile
    constexpr int THW = 12 + 2 * PAD;   // stage-1 pooled window per tile

    float s2phR[4][24];                 // stage-2 pooled (static indices)

    #pragma unroll
    for (int tt = 0; tt < 4; tt++) {    // fully unrolled: all indices const
        // x window: global t = 24*tt - 3*PAD + i (zero outside [0,96))
        float xw[XW];
        #pragma unroll
        for (int i = 0; i < XW; i++) {
            const int t = 24 * tt - 3 * PAD + i;     // compile-time
            xw[i] = (t >= 0 && t < T_LEN) ? xb[(size_t)t * ts] : 0.f;
        }

        if (DO_EXTRA) {                 // orig = pool2^3: 3 outputs per tile
            #pragma unroll
            for (int r = 0; r < 3; r++) {
                float s = 0.f;
                #pragma unroll
                for (int k = 0; k < 8; k++) s += xw[3 * PAD + 8 * r + k];
                frow[3 * tt + r] = __float2bfloat16(s * 0.125f);
            }
        }

        float s2a[4][12];
        #pragma unroll
        for (int oc = 0; oc < 4; oc++) {
            const float bv = bi1[oc];
            #pragma unroll
            for (int q = 0; q < 12; q++) s2a[oc][q] = bv;
        }

        #pragma unroll 1
        for (int ic = 0; ic < 8; ic++) {
            const float bs1 = bS[ic];
            float thw[THW];             // stage-1 pooled window (this ic)
            #pragma unroll
            for (int j = 0; j < THW; j++) {
                const int jg = 12 * tt - PAD + j;    // compile-time
                if (jg < 0 || jg >= 48) { thw[j] = 0.f; continue; }
                float y0 = bs1, y1 = bs1;
                #pragma unroll
                for (int k = 0; k < K; k++) {
                    const float w = wS[ic * K + k];
                    y0 = fmaf(w, xw[2 * j + k], y0);
                    y1 = fmaf(w, xw[2 * j + 1 + k], y1);
                }
                thw[j] = 0.5f * (fmaxf(y0, 0.f) + fmaxf(y1, 0.f));
            }
            #pragma unroll
            for (int q = 0; q < 12; q++) {
                #pragma unroll
                for (int oc = 0; oc < 4; oc++) {
                    float a = s2a[oc][q];
                    #pragma unroll
                    for (int k = 0; k < K; k++)
                        a = fmaf(wi1[(oc * 8 + ic) * K + k], thw[q + k], a);
                    s2a[oc][q] = a;
                }
            }
        }

        // pool stage 2 -> s2phR[oc][6*tt + r]
        #pragma unroll
        for (int oc = 0; oc < 4; oc++)
            #pragma unroll
            for (int r = 0; r < 6; r++)
                s2phR[oc][6 * tt + r] =
                    0.5f * (fmaxf(s2a[oc][2 * r], 0.f) +
                            fmaxf(s2a[oc][2 * r + 1], 0.f));
    }

    // stage 3 (grouped 4->4) + relu + pool2; OOB taps statically dropped
    #pragma unroll 1
    for (int oc = 0; oc < 4; oc++) {
        const float bv = bi2[oc];
        #pragma unroll
        for (int q = 0; q < 12; q++) {
            float y0 = bv, y1 = bv;
            #pragma unroll
            for (int ic = 0; ic < 4; ic++) {
                #pragma unroll
                for (int k = 0; k < K; k++) {
                    const float w = wi2[(oc * 4 + ic) * K + k];
                    const int i0 = 2 * q + k - PAD;       // compile-time
                    const int i1 = 2 * q + 1 + k - PAD;
                    if (i0 >= 0 && i0 < 24) y0 = fmaf(w, s2phR[ic][i0], y0);
                    if (i1 >= 0 && i1 < 24) y1 = fmaf(w, s2phR[ic][i1], y1);
                }
            }
            frow[out_off + oc * 12 + q] =
                __float2bfloat16(0.5f * (fmaxf(y0, 0.f) + fmaxf(y1, 0.f)));
        }
    }
}

__global__ __launch_bounds__(64, 2) void conv_fused_kernel(
    const float* __restrict__ x, int ts, int bs, int cs,
    const float* __restrict__ w_hs, const float* __restrict__ b_hs,
    const float* __restrict__ w_ls, const float* __restrict__ b_ls,
    const float* __restrict__ w_hi1, const float* __restrict__ b_hi1,
    const float* __restrict__ w_hi2, const float* __restrict__ b_hi2,
    const float* __restrict__ w_li1, const float* __restrict__ b_li1,
    const float* __restrict__ w_li2, const float* __restrict__ b_li2,
    __hip_bfloat16* __restrict__ feat)
{
    const int lane = threadIdx.x;
    const int b = blockIdx.x * 64 + lane;
    const int c = blockIdx.y;
    const float* xb = x + (size_t)b * bs + (size_t)c * cs;
    __hip_bfloat16* frow = feat + (size_t)b * KPAD + c * 108;

    if (blockIdx.z == 0) {
        conv_branch<7, false>(xb, ts, w_hs, b_hs,
                              w_hi1 + c * 224, b_hi1 + c * 4,
                              w_hi2 + c * 112, b_hi2 + c * 4, frow, 60);
    } else {
        if (c == 0) {                   // zero K-pad tail once per row
            int4* tail = (int4*)(feat + (size_t)b * KPAD + FIN);
            const int4 z = {0, 0, 0, 0};
            #pragma unroll
            for (int i = 0; i < 5; i++) tail[i] = z;
        }
        conv_branch<3, true>(xb, ts, w_ls, b_ls,
                             w_li1 + c * 96, b_li1 + c * 4,
                             w_li2 + c * 48, b_li2 + c * 4, frow, 12);
    }
}

// ---------------------------------------------------------------------------
// Kernel 3: FC1 GEMM. 8-phase interleave (T3+T4+T5, verified r10) + ROUND-12
// T2 LDS XOR-SWIZZLE. Diagnosis: [256][32] layout = 64B rows -> ds_read_b128
// with per-lane row is an 8-way bank conflict on every A/B fragment load;
// gemm ~175us (~345 TF) by subtraction. T2 pays only at 8-phase (m201/m252)
// -> now applicable. Involution S(byte) = byte ^ (((byte>>7)&7)<<4) within
// each 16KB kh-region (mask bits 4-6 depend only on untouched bits 7-9).
// Rule #21 both-sides discipline: LDS dest stays LINEAR (GLD_LDS req);
// per-lane GLOBAL source pre-permuted by S (chunk' = chunk ^ ((chunk>>3)&7),
// identical mask for both 128-row halves since 512 = 0 mod 8*... bit9 is
// untouched); ds_reads apply S in element form: e ^= ((row>>1)&7)<<3.
// Post-swizzle read pattern = 2-way (free, m136); alignment preserved
// (element bits 0-2 untouched); global coalescing preserved (permutation
// stays within 2-row x 64B groups).
__global__ __launch_bounds__(512, 2) void gemm_kernel(
    const __hip_bfloat16* __restrict__ A,
    const __hip_bfloat16* __restrict__ Bw,
    float* __restrict__ Cm, int kchunk)
{
    __shared__ __align__(16) __hip_bfloat16 lds[2][2][2][8192];  // 128 KiB

    const int tid  = threadIdx.x;
    const int lane = tid & 63;
    const int wid  = tid >> 6;          // 0..7
    const int m0 = blockIdx.y * 256;
    const int n0 = blockIdx.x * 256;
    const int wm = (wid >> 2) * 128;    // 2 wave-rows (128 each)
    const int wn = (wid & 3) * 64;      // 4 wave-cols (64 each)
    const int lr = lane & 15;
    const int quad = lane >> 4;

    // staging with pre-swizzled source: chunk c = tid (and +512) writes LDS
    // linearly at byte c*16; it must carry the data of linear chunk
    // c ^ ((c>>3)&7)  (= S(byte)/16).
    const int csw  = tid ^ ((tid >> 3) & 7);
    const int srow = csw >> 2, scol = (csw & 3) * 8;
    const __hip_bfloat16* gA = A  + (size_t)(m0 + srow) * KPAD + scol;
    const __hip_bfloat16* gB = Bw + (size_t)(n0 + srow) * KPAD + scol;

    f32x4 acc[8][4] = {};

    const int kBeg = blockIdx.z * kchunk;
    const int numt = kchunk >> 6;       // K-steps of 64 (28 for sk=4)

#define STAGE_H(opidx, gptr, kh, kt)                                          \
    do {                                                                      \
        const size_t co = (size_t)(kBeg + (kt) * 64 + (kh) * 32);             \
        GLD_LDS((gptr) + co, &lds[(kt) & 1][opidx][kh][wid * 512]);           \
        GLD_LDS((gptr) + co + (size_t)128 * KPAD,                             \
                &lds[(kt) & 1][opidx][kh][4096 + wid * 512]);                 \
    } while (0)

// swizzled element offset for row r, 16B slot q (reader side)
#define SWZ(r, q) (((r) * 32 + (q) * 8) ^ ((((r) >> 1) & 7) << 3))

    // prologue: stage tile 0's 4 half-tiles in H-stream order
    STAGE_H(0, gA, 0, 0);
    STAGE_H(1, gB, 0, 0);
    STAGE_H(0, gA, 1, 0);
    STAGE_H(1, gB, 1, 0);

    for (int t = 0; t < numt; ++t) {
        const int p = t & 1;
        const bool pf = (t + 1 < numt);

        // ===== entry 0: guards ks=0 data (A-kh0, B-kh0 of tile t) =====
        if (pf) asm volatile("s_waitcnt vmcnt(4)" ::: "memory");
        else    asm volatile("s_waitcnt vmcnt(0)" ::: "memory");
        __builtin_amdgcn_sched_barrier(0);
        __builtin_amdgcn_s_barrier();
        __builtin_amdgcn_sched_barrier(0);
        {
            bf16x8 bfr[4], af[4];
            #pragma unroll
            for (int nn = 0; nn < 4; nn++)
                bfr[nn] = *(const bf16x8*)&lds[p][1][0][
                    SWZ(wn + nn * 16 + lr, quad)];
            #pragma unroll
            for (int i = 0; i < 4; i++)
                af[i] = *(const bf16x8*)&lds[p][0][0][
                    SWZ(wm + i * 16 + lr, quad)];
            if (pf) STAGE_H(0, gA, 0, t + 1);      // H[4(t+1)+0]
            __builtin_amdgcn_s_setprio(1);
            #pragma unroll
            for (int i = 0; i < 4; i++)
                #pragma unroll
                for (int nn = 0; nn < 4; nn++)
                    acc[i][nn] = __builtin_amdgcn_mfma_f32_16x16x32_bf16(
                        af[i], bfr[nn], acc[i][nn], 0, 0, 0);
            __builtin_amdgcn_s_setprio(0);

            // subphase q1: ks0, mt 4-7 (reuse bfr)
            #pragma unroll
            for (int i = 0; i < 4; i++)
                af[i] = *(const bf16x8*)&lds[p][0][0][
                    SWZ(wm + 64 + i * 16 + lr, quad)];
            if (pf) STAGE_H(1, gB, 0, t + 1);      // H[4(t+1)+1]
            __builtin_amdgcn_s_setprio(1);
            #pragma unroll
            for (int i = 0; i < 4; i++)
                #pragma unroll
                for (int nn = 0; nn < 4; nn++)
                    acc[4 + i][nn] = __builtin_amdgcn_mfma_f32_16x16x32_bf16(
                        af[i], bfr[nn], acc[4 + i][nn], 0, 0, 0);
            __builtin_amdgcn_s_setprio(0);
        }

        // ===== entry 1: guards ks=1 data (A-kh1, B-kh1 of tile t) =====
        if (pf) asm volatile("s_waitcnt vmcnt(4)" ::: "memory");
        else    asm volatile("s_waitcnt vmcnt(0)" ::: "memory");
        __builtin_amdgcn_sched_barrier(0);
        __builtin_amdgcn_s_barrier();
        __builtin_amdgcn_sched_barrier(0);
        {
            bf16x8 bfr[4], af[4];
            #pragma unroll
            for (int nn = 0; nn < 4; nn++)
                bfr[nn] = *(const bf16x8*)&lds[p][1][1][
                    SWZ(wn + nn * 16 + lr, quad)];
            #pragma unroll
            for (int i = 0; i < 4; i++)
                af[i] = *(const bf16x8*)&lds[p][0][1][
                    SWZ(wm + i * 16 + lr, quad)];
            if (pf) STAGE_H(0, gA, 1, t + 1);      // H[4(t+1)+2]
            __builtin_amdgcn_s_setprio(1);
            #pragma unroll
            for (int i = 0; i < 4; i++)
                #pragma unroll
                for (int nn = 0; nn < 4; nn++)
                    acc[i][nn] = __builtin_amdgcn_mfma_f32_16x16x32_bf16(
                        af[i], bfr[nn], acc[i][nn], 0, 0, 0);
            __builtin_amdgcn_s_setprio(0);

            // subphase q3: ks1, mt 4-7 (reuse bfr)
            #pragma unroll
            for (int i = 0; i < 4; i++)
                af[i] = *(const bf16x8*)&lds[p][0][1][
                    SWZ(wm + 64 + i * 16 + lr, quad)];
            if (pf) STAGE_H(1, gB, 1, t + 1);      // H[4(t+1)+3]
            __builtin_amdgcn_s_setprio(1);
            #pragma unroll
            for (int i = 0; i < 4; i++)
                #pragma unroll
                for (int nn = 0; nn < 4; nn++)
                    acc[4 + i][nn] = __builtin_amdgcn_mfma_f32_16x16x32_bf16(
                        af[i], bfr[nn], acc[4 + i][nn], 0, 0, 0);
            __builtin_amdgcn_s_setprio(0);
        }
    }
#undef SWZ
#undef STAGE_H

    // epilogue: C/D layout col = lane&15, row = quad*4 + reg
    float* Cs = Cm + (size_t)blockIdx.z * NPAD * NPAD;
    #pragma unroll
    for (int mt = 0; mt < 8; mt++) {
        #pragma unroll
        for (int nn = 0; nn < 4; nn++) {
            const int col = n0 + wn + nn * 16 + lr;
            const int rb  = m0 + wm + mt * 16 + quad * 4;
            #pragma unroll
            for (int r = 0; r < 4; r++)
                Cs[(size_t)(rb + r) * NPAD + col] = acc[mt][nn][r];
        }
    }
}

// ---------------------------------------------------------------------------
// Kernel 4: reduce split-K slabs + bias + relu, then FC2. One block per row.
__global__ __launch_bounds__(256) void fc2_kernel(
    const float* __restrict__ h1, const float* __restrict__ b1,
    const float* __restrict__ w2, const float* __restrict__ b2,
    float* __restrict__ out, int nslab)
{
    const int b = blockIdx.x;
    const int tid = threadIdx.x;
    float acc[NCLS];
    #pragma unroll
    for (int o = 0; o < NCLS; o++) acc[o] = 0.f;
    for (int n = tid; n < NFC1; n += 256) {
        float hv = b1[n];
        for (int s = 0; s < nslab; s++)
            hv += h1[(size_t)s * NPAD * NPAD + (size_t)b * NPAD + n];
        float h = fmaxf(hv, 0.f);
        #pragma unroll
        for (int o = 0; o < NCLS; o++)
            acc[o] = fmaf(h, w2[o * NFC1 + n], acc[o]);
    }
    __shared__ float red[4][NCLS];
    #pragma unroll
    for (int o = 0; o < NCLS; o++) {
        float v = acc[o];
        #pragma unroll
        for (int s = 32; s > 0; s >>= 1) v += __shfl_down(v, s);
        if ((tid & 63) == 0) red[tid >> 6][o] = v;
    }
    __syncthreads();
    if (tid < NCLS)
        out[b * NCLS + tid] = red[0][tid] + red[1][tid] + red[2][tid] +
                              red[3][tid] + b2[tid];
}

// ---------------------------------------------------------------------------
extern "C" void kernel_launch(void* const* d_in, const int* in_sizes, int n_in,
                              void* d_out, int out_size, void* d_ws, size_t ws_size,
                              hipStream_t stream)
{
    (void)n_in; (void)out_size;
    const float* x     = (const float*)d_in[0];
    const float* w_hs  = (const float*)d_in[1];
    const float* b_hs  = (const float*)d_in[2];
    const float* w_ls  = (const float*)d_in[3];
    const float* b_ls  = (const float*)d_in[4];
    const float* w_hi1 = (const float*)d_in[5];
    const float* b_hi1 = (const float*)d_in[6];
    const float* w_hi2 = (const float*)d_in[7];
    const float* b_hi2 = (const float*)d_in[8];
    const float* w_li1 = (const float*)d_in[9];
    const float* b_li1 = (const float*)d_in[10];
    const float* w_li2 = (const float*)d_in[11];
    const float* b_li2 = (const float*)d_in[12];
    const float* w_fc1 = (const float*)d_in[13];
    const float* b_fc1 = (const float*)d_in[14];
    const float* w_fc2 = (const float*)d_in[15];
    const float* b_fc2 = (const float*)d_in[16];
    float* out = (float*)d_out;

    const int B = in_sizes[0] / (T_LEN * C_CH);    // 2048

    char* ws = (char*)d_ws;
    const size_t featB = (size_t)B * KPAD * 2;         // 29.4 MB
    const size_t wbB   = (size_t)NPAD * KPAD * 2;      // 29.4 MB
    const size_t slabB = (size_t)NPAD * NPAD * 4;      // 16.8 MB
    const size_t xtB   = (size_t)T_LEN * C_CH * B * 4; // 51.9 MB
    const size_t base2 = featB + wbB;

    __hip_bfloat16* feat = (__hip_bfloat16*)ws;
    __hip_bfloat16* wb   = (__hip_bfloat16*)(ws + featB);
    float* h1            = (float*)(ws + base2);

    const int sk = (ws_size >= base2 + 4 * slabB) ? 4 : 2;
    const bool use_xt = (ws_size >= base2 + sk * slabB + xtB);
    float* xT = (float*)(ws + base2 + sk * slabB);

    pad_w_kernel<<<dim3((NPAD * 896) / 256), 256, 0, stream>>>(w_fc1, wb);

    const float* cx = x;
    int ts = C_CH, bsi = T_LEN * C_CH, cs = 1;
    if (use_xt) {
        transpose_kernel<<<dim3(99, B / 64), 256, 0, stream>>>(x, xT, B);
        cx = xT; ts = C_CH * B; bsi = 1; cs = B;
    }
    conv_fused_kernel<<<dim3(B / 64, C_CH, 2), 64, 0, stream>>>(
        cx, ts, bsi, cs, w_hs, b_hs, w_ls, b_ls,
        w_hi1, b_hi1, w_hi2, b_hi2, w_li1, b_li1, w_li2, b_li2, feat);
    gemm_kernel<<<dim3(NPAD / 256, B / 256, sk), 512, 0, stream>>>(
        feat, wb, h1, KPAD / sk);
    fc2_kernel<<<dim3(B), 256, 0, stream>>>(h1, b_fc1, w_fc2, b_fc2, out, sk);
}

// Round 13
// 398.956 us; speedup vs baseline: 1.1219x; 1.0132x over previous
//
#include <hip/hip_runtime.h>
#include <hip/hip_bf16.h>

#define T_LEN 96
#define C_CH  66
#define FIN   7128   // 9*66*12
#define KPAD  7168   // 224*32
#define NFC1  1936
#define NPAD  2048
#define NCLS  14

typedef __bf16 bf16x8 __attribute__((ext_vector_type(8)));
typedef float  f32x4  __attribute__((ext_vector_type(4)));

#define GLD_LDS(gp, lp) __builtin_amdgcn_global_load_lds(                     \
    (__attribute__((address_space(1))) void*)(gp),                            \
    (__attribute__((address_space(3))) void*)(lp), 16, 0, 0)

// ---------------------------------------------------------------------------
// Kernel 0+1 merged (ROUND-13): transpose x -> xT AND w_fc1 -> bf16 pad, one
// dispatch. Both are BW-bound and independent; merging removes one launch
// boundary + ramp/drain. Transpose blocks FIRST (they feed conv, the next
// kernel). Block-uniform branch -> no divergence; __syncthreads only on the
// transpose path (uniform per block).
__global__ __launch_bounds__(256) void prep_kernel(
    const float* __restrict__ x, float* __restrict__ xT, int B,
    const float* __restrict__ w, __hip_bfloat16* __restrict__ wb)
{
    const int nTrans = 99 * (B >> 6);          // 3168 transpose blocks
    const int blk = blockIdx.x;
    if (blk < nTrans) {
        __shared__ float tile[64][65];
        const int by = blk / 99, bx = blk - by * 99;
        const int t = threadIdx.x & 63;
        const int wv = threadIdx.x >> 6;
        const int tc0 = bx * 64;
        const int b0  = by * 64;
        #pragma unroll
        for (int j = 0; j < 16; j++) {
            const int r = wv * 16 + j;
            tile[r][t] = x[(size_t)(b0 + r) * (T_LEN * C_CH) + tc0 + t];
        }
        __syncthreads();
        #pragma unroll
        for (int j = 0; j < 16; j++) {
            const int r = wv * 16 + j;
            xT[(size_t)(tc0 + r) * B + b0 + t] = tile[t][r];
        }
    } else {
        int idx = (blk - nTrans) * 256 + threadIdx.x;  // total 2048*896
        int row = idx / 896;
        int cc  = idx - row * 896;                     // 896 chunks of 8
        float4 a = {0.f, 0.f, 0.f, 0.f}, b = {0.f, 0.f, 0.f, 0.f};
        if (row < NFC1 && cc < 891) {                  // 891*8 = 7128
            const float4* src = (const float4*)(w + (size_t)row * FIN + cc * 8);
            a = src[0];
            b = src[1];
        }
        __align__(16) __hip_bfloat16 v[8];
        v[0] = __float2bfloat16(a.x); v[1] = __float2bfloat16(a.y);
        v[2] = __float2bfloat16(a.z); v[3] = __float2bfloat16(a.w);
        v[4] = __float2bfloat16(b.x); v[5] = __float2bfloat16(b.y);
        v[6] = __float2bfloat16(b.z); v[7] = __float2bfloat16(b.w);
        *(int4*)(wb + (size_t)row * KPAD + cc * 8) = *(const int4*)v;
    }
}

// ---------------------------------------------------------------------------
// Kernel 2: conv branches — EXACT round-0 version (174us, VGPR=128), both
// branches in ONE launch (blockIdx.z slowest -> K=7 blocks dispatch first =
// LPT-good). DO NOT TOUCH (6 interventions, all losses).
// One lane = one (b, c); grid (B/64, C, 2): z=0 K=7, z=1 K=3.
template <int K, bool DO_EXTRA>
__device__ __forceinline__ void conv_branch(
    const float* __restrict__ xb, int ts,
    const float* __restrict__ wS, const float* __restrict__ bS,
    const float* __restrict__ wi1, const float* __restrict__ bi1,
    const float* __restrict__ wi2, const float* __restrict__ bi2,
    __hip_bfloat16* __restrict__ frow, int out_off)
{
    constexpr int PAD = K / 2;
    constexpr int XW  = 24 + 6 * PAD;   // x window per tile
    constexpr int THW = 12 + 2 * PAD;   // stage-1 pooled window per tile

    float s2phR[4][24];                 // stage-2 pooled (static indices)

    #pragma unroll
    for (int tt = 0; tt < 4; tt++) {    // fully unrolled: all indices const
        // x window: global t = 24*tt - 3*PAD + i (zero outside [0,96))
        float xw[XW];
        #pragma unroll
        for (int i = 0; i < XW; i++) {
            const int t = 24 * tt - 3 * PAD + i;     // compile-time
            xw[i] = (t >= 0 && t < T_LEN) ? xb[(size_t)t * ts] : 0.f;
        }

        if (DO_EXTRA) {                 // orig = pool2^3: 3 outputs per tile
            #pragma unroll
            for (int r = 0; r < 3; r++) {
                float s = 0.f;
                #pragma unroll
                for (int k = 0; k < 8; k++) s += xw[3 * PAD + 8 * r + k];
                frow[3 * tt + r] = __float2bfloat16(s * 0.125f);
            }
        }

        float s2a[4][12];
        #pragma unroll
        for (int oc = 0; oc < 4; oc++) {
            const float bv = bi1[oc];
            #pragma unroll
            for (int q = 0; q < 12; q++) s2a[oc][q] = bv;
        }

        #pragma unroll 1
        for (int ic = 0; ic < 8; ic++) {
            const float bs1 = bS[ic];
            float thw[THW];             // stage-1 pooled window (this ic)
            #pragma unroll
            for (int j = 0; j < THW; j++) {
                const int jg = 12 * tt - PAD + j;    // compile-time
                if (jg < 0 || jg >= 48) { thw[j] = 0.f; continue; }
                float y0 = bs1, y1 = bs1;
                #pragma unroll
                for (int k = 0; k < K; k++) {
                    const float w = wS[ic * K + k];
                    y0 = fmaf(w, xw[2 * j + k], y0);
                    y1 = fmaf(w, xw[2 * j + 1 + k], y1);
                }
                thw[j] = 0.5f * (fmaxf(y0, 0.f) + fmaxf(y1, 0.f));
            }
            #pragma unroll
            for (int q = 0; q < 12; q++) {
                #pragma unroll
                for (int oc = 0; oc < 4; oc++) {
                    float a = s2a[oc][q];
                    #pragma unroll
                    for (int k = 0; k < K; k++)
                        a = fmaf(wi1[(oc * 8 + ic) * K + k], thw[q + k], a);
                    s2a[oc][q] = a;
                }
            }
        }

        // pool stage 2 -> s2phR[oc][6*tt + r]
        #pragma unroll
        for (int oc = 0; oc < 4; oc++)
            #pragma unroll
            for (int r = 0; r < 6; r++)
                s2phR[oc][6 * tt + r] =
                    0.5f * (fmaxf(s2a[oc][2 * r], 0.f) +
                            fmaxf(s2a[oc][2 * r + 1], 0.f));
    }

    // stage 3 (grouped 4->4) + relu + pool2; OOB taps statically dropped
    #pragma unroll 1
    for (int oc = 0; oc < 4; oc++) {
        const float bv = bi2[oc];
        #pragma unroll
        for (int q = 0; q < 12; q++) {
            float y0 = bv, y1 = bv;
            #pragma unroll
            for (int ic = 0; ic < 4; ic++) {
                #pragma unroll
                for (int k = 0; k < K; k++) {
                    const float w = wi2[(oc * 4 + ic) * K + k];
                    const int i0 = 2 * q + k - PAD;       // compile-time
                    const int i1 = 2 * q + 1 + k - PAD;
                    if (i0 >= 0 && i0 < 24) y0 = fmaf(w, s2phR[ic][i0], y0);
                    if (i1 >= 0 && i1 < 24) y1 = fmaf(w, s2phR[ic][i1], y1);
                }
            }
            frow[out_off + oc * 12 + q] =
                __float2bfloat16(0.5f * (fmaxf(y0, 0.f) + fmaxf(y1, 0.f)));
        }
    }
}

__global__ __launch_bounds__(64, 2) void conv_fused_kernel(
    const float* __restrict__ x, int ts, int bs, int cs,
    const float* __restrict__ w_hs, const float* __restrict__ b_hs,
    const float* __restrict__ w_ls, const float* __restrict__ b_ls,
    const float* __restrict__ w_hi1, const float* __restrict__ b_hi1,
    const float* __restrict__ w_hi2, const float* __restrict__ b_hi2,
    const float* __restrict__ w_li1, const float* __restrict__ b_li1,
    const float* __restrict__ w_li2, const float* __restrict__ b_li2,
    __hip_bfloat16* __restrict__ feat)
{
    const int lane = threadIdx.x;
    const int b = blockIdx.x * 64 + lane;
    const int c = blockIdx.y;
    const float* xb = x + (size_t)b * bs + (size_t)c * cs;
    __hip_bfloat16* frow = feat + (size_t)b * KPAD + c * 108;

    if (blockIdx.z == 0) {
        conv_branch<7, false>(xb, ts, w_hs, b_hs,
                              w_hi1 + c * 224, b_hi1 + c * 4,
                              w_hi2 + c * 112, b_hi2 + c * 4, frow, 60);
    } else {
        if (c == 0) {                   // zero K-pad tail once per row
            int4* tail = (int4*)(feat + (size_t)b * KPAD + FIN);
            const int4 z = {0, 0, 0, 0};
            #pragma unroll
            for (int i = 0; i < 5; i++) tail[i] = z;
        }
        conv_branch<3, true>(xb, ts, w_ls, b_ls,
                             w_li1 + c * 96, b_li1 + c * 4,
                             w_li2 + c * 48, b_li2 + c * 4, frow, 12);
    }
}

// ---------------------------------------------------------------------------
// Kernel 3: FC1 GEMM. 8-phase interleave (T3+T4+T5, r10) + T2 swizzle (r12,
// neutral but kept) + ROUND-13 XCD SUPERTILE REMAP (T1 variant): hardware
// XCD = wgid%8 = blockIdx.x; default mapping read every A panel on all 8
// XCDs (A L3->L2 traffic 235MB, B 29MB). Remap so XCD s owns a 2-mtile x
// 4-ntile supertile: mt=(sup>>1)*2+(loc>>2), nt=(sup&1)*4+(loc&3)
// (bijective; inverse sup=(mt>>1)*2+(nt>>2), loc=(mt&1)*4+(nt&3)).
// -> A dup 2x, B dup 4x = 176MB total; per-k-step XCD working set 192KB
// (L2-fit). z unchanged (64z = 0 mod 8, same XCD, disjoint k-range).
__global__ __launch_bounds__(512, 2) void gemm_kernel(
    const __hip_bfloat16* __restrict__ A,
    const __hip_bfloat16* __restrict__ Bw,
    float* __restrict__ Cm, int kchunk)
{
    __shared__ __align__(16) __hip_bfloat16 lds[2][2][2][8192];  // 128 KiB

    const int tid  = threadIdx.x;
    const int lane = tid & 63;
    const int wid  = tid >> 6;          // 0..7
    const int sup = blockIdx.x;         // = XCD (wgid%8)
    const int loc = blockIdx.y;
    const int m0 = ((sup >> 1) * 2 + (loc >> 2)) * 256;
    const int n0 = ((sup & 1) * 4 + (loc & 3)) * 256;
    const int wm = (wid >> 2) * 128;    // 2 wave-rows (128 each)
    const int wn = (wid & 3) * 64;      // 4 wave-cols (64 each)
    const int lr = lane & 15;
    const int quad = lane >> 4;

    // staging with pre-swizzled source: chunk c = tid (and +512) writes LDS
    // linearly at byte c*16; it carries data of linear chunk c ^ ((c>>3)&7).
    const int csw  = tid ^ ((tid >> 3) & 7);
    const int srow = csw >> 2, scol = (csw & 3) * 8;
    const __hip_bfloat16* gA = A  + (size_t)(m0 + srow) * KPAD + scol;
    const __hip_bfloat16* gB = Bw + (size_t)(n0 + srow) * KPAD + scol;

    f32x4 acc[8][4] = {};

    const int kBeg = blockIdx.z * kchunk;
    const int numt = kchunk >> 6;       // K-steps of 64 (28 for sk=4)

#define STAGE_H(opidx, gptr, kh, kt)                                          \
    do {                                                                      \
        const size_t co = (size_t)(kBeg + (kt) * 64 + (kh) * 32);             \
        GLD_LDS((gptr) + co, &lds[(kt) & 1][opidx][kh][wid * 512]);           \
        GLD_LDS((gptr) + co + (size_t)128 * KPAD,                             \
                &lds[(kt) & 1][opidx][kh][4096 + wid * 512]);                 \
    } while (0)

// swizzled element offset for row r, 16B slot q (reader side)
#define SWZ(r, q) (((r) * 32 + (q) * 8) ^ ((((r) >> 1) & 7) << 3))

    // prologue: stage tile 0's 4 half-tiles in H-stream order
    STAGE_H(0, gA, 0, 0);
    STAGE_H(1, gB, 0, 0);
    STAGE_H(0, gA, 1, 0);
    STAGE_H(1, gB, 1, 0);

    for (int t = 0; t < numt; ++t) {
        const int p = t & 1;
        const bool pf = (t + 1 < numt);

        // ===== entry 0: guards ks=0 data (A-kh0, B-kh0 of tile t) =====
        if (pf) asm volatile("s_waitcnt vmcnt(4)" ::: "memory");
        else    asm volatile("s_waitcnt vmcnt(0)" ::: "memory");
        __builtin_amdgcn_sched_barrier(0);
        __builtin_amdgcn_s_barrier();
        __builtin_amdgcn_sched_barrier(0);
        {
            bf16x8 bfr[4], af[4];
            #pragma unroll
            for (int nn = 0; nn < 4; nn++)
                bfr[nn] = *(const bf16x8*)&lds[p][1][0][
                    SWZ(wn + nn * 16 + lr, quad)];
            #pragma unroll
            for (int i = 0; i < 4; i++)
                af[i] = *(const bf16x8*)&lds[p][0][0][
                    SWZ(wm + i * 16 + lr, quad)];
            if (pf) STAGE_H(0, gA, 0, t + 1);      // H[4(t+1)+0]
            __builtin_amdgcn_s_setprio(1);
            #pragma unroll
            for (int i = 0; i < 4; i++)
                #pragma unroll
                for (int nn = 0; nn < 4; nn++)
                    acc[i][nn] = __builtin_amdgcn_mfma_f32_16x16x32_bf16(
                        af[i], bfr[nn], acc[i][nn], 0, 0, 0);
            __builtin_amdgcn_s_setprio(0);

            // subphase q1: ks0, mt 4-7 (reuse bfr)
            #pragma unroll
            for (int i = 0; i < 4; i++)
                af[i] = *(const bf16x8*)&lds[p][0][0][
                    SWZ(wm + 64 + i * 16 + lr, quad)];
            if (pf) STAGE_H(1, gB, 0, t + 1);      // H[4(t+1)+1]
            __builtin_amdgcn_s_setprio(1);
            #pragma unroll
            for (int i = 0; i < 4; i++)
                #pragma unroll
                for (int nn = 0; nn < 4; nn++)
                    acc[4 + i][nn] = __builtin_amdgcn_mfma_f32_16x16x32_bf16(
                        af[i], bfr[nn], acc[4 + i][nn], 0, 0, 0);
            __builtin_amdgcn_s_setprio(0);
        }

        // ===== entry 1: guards ks=1 data (A-kh1, B-kh1 of tile t) =====
        if (pf) asm volatile("s_waitcnt vmcnt(4)" ::: "memory");
        else    asm volatile("s_waitcnt vmcnt(0)" ::: "memory");
        __builtin_amdgcn_sched_barrier(0);
        __builtin_amdgcn_s_barrier();
        __builtin_amdgcn_sched_barrier(0);
        {
            bf16x8 bfr[4], af[4];
            #pragma unroll
            for (int nn = 0; nn < 4; nn++)
                bfr[nn] = *(const bf16x8*)&lds[p][1][1][
                    SWZ(wn + nn * 16 + lr, quad)];
            #pragma unroll
            for (int i = 0; i < 4; i++)
                af[i] = *(const bf16x8*)&lds[p][0][1][
                    SWZ(wm + i * 16 + lr, quad)];
            if (pf) STAGE_H(0, gA, 1, t + 1);      // H[4(t+1)+2]
            __builtin_amdgcn_s_setprio(1);
            #pragma unroll
            for (int i = 0; i < 4; i++)
                #pragma unroll
                for (int nn = 0; nn < 4; nn++)
                    acc[i][nn] = __builtin_amdgcn_mfma_f32_16x16x32_bf16(
                        af[i], bfr[nn], acc[i][nn], 0, 0, 0);
            __builtin_amdgcn_s_setprio(0);

            // subphase q3: ks1, mt 4-7 (reuse bfr)
            #pragma unroll
            for (int i = 0; i < 4; i++)
                af[i] = *(const bf16x8*)&lds[p][0][1][
                    SWZ(wm + 64 + i * 16 + lr, quad)];
            if (pf) STAGE_H(1, gB, 1, t + 1);      // H[4(t+1)+3]
            __builtin_amdgcn_s_setprio(1);
            #pragma unroll
            for (int i = 0; i < 4; i++)
                #pragma unroll
                for (int nn = 0; nn < 4; nn++)
                    acc[4 + i][nn] = __builtin_amdgcn_mfma_f32_16x16x32_bf16(
                        af[i], bfr[nn], acc[4 + i][nn], 0, 0, 0);
            __builtin_amdgcn_s_setprio(0);
        }
    }
#undef SWZ
#undef STAGE_H

    // epilogue: C/D layout col = lane&15, row = quad*4 + reg
    float* Cs = Cm + (size_t)blockIdx.z * NPAD * NPAD;
    #pragma unroll
    for (int mt = 0; mt < 8; mt++) {
        #pragma unroll
        for (int nn = 0; nn < 4; nn++) {
            const int col = n0 + wn + nn * 16 + lr;
            const int rb  = m0 + wm + mt * 16 + quad * 4;
            #pragma unroll
            for (int r = 0; r < 4; r++)
                Cs[(size_t)(rb + r) * NPAD + col] = acc[mt][nn][r];
        }
    }
}

// ---------------------------------------------------------------------------
// Kernel 4: reduce split-K slabs + bias + relu, then FC2. One block per row.
__global__ __launch_bounds__(256) void fc2_kernel(
    const float* __restrict__ h1, const float* __restrict__ b1,
    const float* __restrict__ w2, const float* __restrict__ b2,
    float* __restrict__ out, int nslab)
{
    const int b = blockIdx.x;
    const int tid = threadIdx.x;
    float acc[NCLS];
    #pragma unroll
    for (int o = 0; o < NCLS; o++) acc[o] = 0.f;
    for (int n = tid; n < NFC1; n += 256) {
        float hv = b1[n];
        for (int s = 0; s < nslab; s++)
            hv += h1[(size_t)s * NPAD * NPAD + (size_t)b * NPAD + n];
        float h = fmaxf(hv, 0.f);
        #pragma unroll
        for (int o = 0; o < NCLS; o++)
            acc[o] = fmaf(h, w2[o * NFC1 + n], acc[o]);
    }
    __shared__ float red[4][NCLS];
    #pragma unroll
    for (int o = 0; o < NCLS; o++) {
        float v = acc[o];
        #pragma unroll
        for (int s = 32; s > 0; s >>= 1) v += __shfl_down(v, s);
        if ((tid & 63) == 0) red[tid >> 6][o] = v;
    }
    __syncthreads();
    if (tid < NCLS)
        out[b * NCLS + tid] = red[0][tid] + red[1][tid] + red[2][tid] +
                              red[3][tid] + b2[tid];
}

// ---------------------------------------------------------------------------
extern "C" void kernel_launch(void* const* d_in, const int* in_sizes, int n_in,
                              void* d_out, int out_size, void* d_ws, size_t ws_size,
                              hipStream_t stream)
{
    (void)n_in; (void)out_size;
    const float* x     = (const float*)d_in[0];
    const float* w_hs  = (const float*)d_in[1];
    const float* b_hs  = (const float*)d_in[2];
    const float* w_ls  = (const float*)d_in[3];
    const float* b_ls  = (const float*)d_in[4];
    const float* w_hi1 = (const float*)d_in[5];
    const float* b_hi1 = (const float*)d_in[6];
    const float* w_hi2 = (const float*)d_in[7];
    const float* b_hi2 = (const float*)d_in[8];
    const float* w_li1 = (const float*)d_in[9];
    const float* b_li1 = (const float*)d_in[10];
    const float* w_li2 = (const float*)d_in[11];
    const float* b_li2 = (const float*)d_in[12];
    const float* w_fc1 = (const float*)d_in[13];
    const float* b_fc1 = (const float*)d_in[14];
    const float* w_fc2 = (const float*)d_in[15];
    const float* b_fc2 = (const float*)d_in[16];
    float* out = (float*)d_out;

    const int B = in_sizes[0] / (T_LEN * C_CH);    // 2048

    char* ws = (char*)d_ws;
    const size_t featB = (size_t)B * KPAD * 2;         // 29.4 MB
    const size_t wbB   = (size_t)NPAD * KPAD * 2;      // 29.4 MB
    const size_t slabB = (size_t)NPAD * NPAD * 4;      // 16.8 MB
    const size_t xtB   = (size_t)T_LEN * C_CH * B * 4; // 51.9 MB
    const size_t base2 = featB + wbB;

    __hip_bfloat16* feat = (__hip_bfloat16*)ws;
    __hip_bfloat16* wb   = (__hip_bfloat16*)(ws + featB);
    float* h1            = (float*)(ws + base2);

    const int sk = (ws_size >= base2 + 4 * slabB) ? 4 : 2;
    const bool use_xt = (ws_size >= base2 + sk * slabB + xtB);
    float* xT = (float*)(ws + base2 + sk * slabB);

    const float* cx = x;
    int ts = C_CH, bsi = T_LEN * C_CH, cs = 1;
    if (use_xt) {
        // merged transpose + pad_w (transpose blocks first)
        prep_kernel<<<dim3(99 * (B / 64) + (NPAD * 896) / 256), 256, 0,
                      stream>>>(x, xT, B, w_fc1, wb);
        cx = xT; ts = C_CH * B; bsi = 1; cs = B;
    } else {
        prep_kernel<<<dim3((NPAD * 896) / 256), 256, 0, stream>>>(
            x, xT, 0, w_fc1, wb);      // B=0 -> all blocks take pad_w path
    }
    conv_fused_kernel<<<dim3(B / 64, C_CH, 2), 64, 0, stream>>>(
        cx, ts, bsi, cs, w_hs, b_hs, w_ls, b_ls,
        w_hi1, b_hi1, w_hi2, b_hi2, w_li1, b_li1, w_li2, b_li2, feat);
    gemm_kernel<<<dim3(NPAD / 256, B / 256, sk), 512, 0, stream>>>(
        feat, wb, h1, KPAD / sk);
    fc2_kernel<<<dim3(B), 256, 0, stream>>>(h1, b_fc1, w_fc2, b_fc2, out, sk);
}